// Round 9
// baseline (348.725 us; speedup 1.0000x reference)
//
#include <hip/hip_runtime.h>

// (B,C,T)=(8,512,1024), H=8, D=64, K=64, REL=129. I/O fp32; internal bf16.
#define B_   8
#define C_   512
#define T_   1024
#define H_   8
#define D_   64
#define K_   64
#define REL_ 129

typedef unsigned short u16;
typedef __attribute__((ext_vector_type(8))) short short8;   // 8 bf16 (4 VGPRs)
typedef __attribute__((ext_vector_type(4))) float f32x4;

__device__ __forceinline__ float b2f(u16 u) {
    return __uint_as_float(((unsigned)u) << 16);
}
__device__ __forceinline__ u16 f2b(float f) {
    unsigned x = __float_as_uint(f);
    x += 0x7fffu + ((x >> 16) & 1u);   // RNE
    return (u16)(x >> 16);
}

// ---------------------------------------------------------------------------
// Kernel 0a: cast + transpose x -> xt[b][t][c] bf16
// ---------------------------------------------------------------------------
__global__ __launch_bounds__(256) void cast_x_kernel(
    const float* __restrict__ x, u16* __restrict__ xt)
{
    __shared__ u16 tile[64][72];
    const int t0 = blockIdx.x * 64, c0 = blockIdx.y * 64, b = blockIdx.z;
    const int tid = threadIdx.x;
    const int f = tid & 15, r0 = tid >> 4;
#pragma unroll
    for (int p = 0; p < 4; ++p) {
        const int c = r0 + p * 16;
        const float4 v = *(const float4*)(x + ((size_t)b * C_ + c0 + c) * T_ + t0 + f * 4);
        tile[c][f * 4 + 0] = f2b(v.x);
        tile[c][f * 4 + 1] = f2b(v.y);
        tile[c][f * 4 + 2] = f2b(v.z);
        tile[c][f * 4 + 3] = f2b(v.w);
    }
    __syncthreads();
#pragma unroll
    for (int p = 0; p < 4; ++p) {
        const int t = r0 + p * 16;
        ushort4 u;
        u.x = tile[f * 4 + 0][t];
        u.y = tile[f * 4 + 1][t];
        u.z = tile[f * 4 + 2][t];
        u.w = tile[f * 4 + 3][t];
        *(ushort4*)(xt + ((size_t)b * T_ + t0 + t) * C_ + c0 + f * 4) = u;
    }
}

// ---------------------------------------------------------------------------
// Kernel 0b: cast Wq,Wk,Wv,Wo -> Wh[4][512][512] bf16.
// ---------------------------------------------------------------------------
__global__ __launch_bounds__(256) void cast_w_kernel(
    const float* __restrict__ Wq, const float* __restrict__ Wk,
    const float* __restrict__ Wv, const float* __restrict__ Wo,
    u16* __restrict__ Wh)
{
    const int gid = blockIdx.x * 256 + threadIdx.x;
    const int s = gid >> 16;
    const int off = (gid & 65535) * 4;
    const float* W = (s == 0) ? Wq : (s == 1) ? Wk : (s == 2) ? Wv : Wo;
    const float4 v = *(const float4*)(W + off);
    ushort4 u;
    u.x = f2b(v.x); u.y = f2b(v.y); u.z = f2b(v.z); u.w = f2b(v.w);
    *(ushort4*)(Wh + ((size_t)s << 18) + off) = u;
}

// ---------------------------------------------------------------------------
// Kernel 0c: rel-embedding prep.
//   ervt[d][rel] bf16 [64][160] (rel>=129 zero)
//   erkb[rel][d] bf16 [129][64]
// ---------------------------------------------------------------------------
__global__ __launch_bounds__(256) void cast_rel_kernel(
    const float* __restrict__ erk, const float* __restrict__ erv,
    u16* __restrict__ ervt, u16* __restrict__ erkb)
{
    const int idx = blockIdx.x * 256 + threadIdx.x;
    if (idx < 64 * 160) {
        const int d = idx / 160, rel = idx % 160;
        ervt[idx] = (rel < REL_) ? f2b(erv[rel * D_ + d]) : (u16)0;
    } else {
        const int j = idx - 64 * 160;
        if (j < REL_ * D_) erkb[j] = f2b(erk[j]);
    }
}

// ---------------------------------------------------------------------------
// Kernel 1: QKV projection, 128x128 tile, BK=64, A+B staged in LDS.
// grid = (T/128, 4, 3*B) -> (8,4,24); block 256 (2x2 wave quadrants of 64).
// out[t,o] = sum_c xt[b][t][c] * W[sel][o][c] + bias; o-tile covers 2 heads.
// ---------------------------------------------------------------------------
__global__ __launch_bounds__(256) void proj_mfma(
    const u16* __restrict__ xt, const u16* __restrict__ Wh,
    const float* __restrict__ bq, const float* __restrict__ bk, const float* __restrict__ bv,
    u16* __restrict__ qh, u16* __restrict__ kh, u16* __restrict__ vt)
{
    __shared__ u16 As[128][72];
    __shared__ u16 Bs[128][72];

    const int t0 = blockIdx.x * 128;
    const int oy = blockIdx.y;                 // o0 = oy*128
    const int sel = blockIdx.z >> 3;
    const int b   = blockIdx.z & 7;
    const int tid = threadIdx.x, wave = tid >> 6, lane = tid & 63;
    const int quad = lane >> 4, l16 = lane & 15;
    const int wr = wave >> 1, wc = wave & 1;

    const u16* Abase = xt + (((size_t)b * T_ + t0) << 9);
    const u16* Bbase = Wh + ((size_t)sel << 18) + (((size_t)oy * 128) << 9);

    int srow[4], scol[4];
#pragma unroll
    for (int p = 0; p < 4; ++p) {
        const int idx = p * 256 + tid;
        srow[p] = idx >> 3;
        scol[p] = (idx & 7) * 8;
    }

    f32x4 acc[4][4];
#pragma unroll
    for (int mi = 0; mi < 4; ++mi)
#pragma unroll
        for (int ni = 0; ni < 4; ++ni) acc[mi][ni] = (f32x4){0.f, 0.f, 0.f, 0.f};

    uint4 ra[4], rb[4];
#pragma unroll
    for (int p = 0; p < 4; ++p) {
        ra[p] = *(const uint4*)(Abase + ((size_t)srow[p] << 9) + scol[p]);
        rb[p] = *(const uint4*)(Bbase + ((size_t)srow[p] << 9) + scol[p]);
    }
#pragma unroll 1
    for (int kt = 0; kt < 8; ++kt) {
        __syncthreads();
#pragma unroll
        for (int p = 0; p < 4; ++p) {
            *(uint4*)&As[srow[p]][scol[p]] = ra[p];
            *(uint4*)&Bs[srow[p]][scol[p]] = rb[p];
        }
        __syncthreads();
        if (kt < 7) {
            const int cn = (kt + 1) * 64;
#pragma unroll
            for (int p = 0; p < 4; ++p) {
                ra[p] = *(const uint4*)(Abase + ((size_t)srow[p] << 9) + cn + scol[p]);
                rb[p] = *(const uint4*)(Bbase + ((size_t)srow[p] << 9) + cn + scol[p]);
            }
        }
#pragma unroll
        for (int kk = 0; kk < 64; kk += 32) {
            short8 af[4], bf[4];
#pragma unroll
            for (int mi = 0; mi < 4; ++mi)
                af[mi] = *(const short8*)(&As[wr * 64 + mi * 16 + l16][kk + quad * 8]);
#pragma unroll
            for (int ni = 0; ni < 4; ++ni)
                bf[ni] = *(const short8*)(&Bs[wc * 64 + ni * 16 + l16][kk + quad * 8]);
#pragma unroll
            for (int mi = 0; mi < 4; ++mi)
#pragma unroll
                for (int ni = 0; ni < 4; ++ni)
                    acc[mi][ni] = __builtin_amdgcn_mfma_f32_16x16x32_bf16(af[mi], bf[ni], acc[mi][ni], 0, 0, 0);
        }
    }

    const float* bias = (sel == 0) ? bq : (sel == 1) ? bk : bv;
    const int h = oy * 2 + wc;
    const int bh = b * 8 + h;
#pragma unroll
    for (int ni = 0; ni < 4; ++ni) {
        const int d = ni * 16 + l16;
        const float bo = bias[h * 64 + d];
#pragma unroll
        for (int mi = 0; mi < 4; ++mi) {
#pragma unroll
            for (int rix = 0; rix < 4; ++rix) {
                const int t = t0 + wr * 64 + mi * 16 + quad * 4 + rix;
                const u16 val = f2b(acc[mi][ni][rix] + bo);
                if (sel == 2) {
                    vt[(((size_t)bh * 64 + d) << 10) + t] = val;
                } else {
                    u16* dst = sel ? kh : qh;
                    dst[(((size_t)bh * T_ + t) << 6) + d] = val;
                }
            }
        }
    }
}

// ---------------------------------------------------------------------------
// Kernel 2: MFMA attention, 16 q-rows/block, deferred normalization.
// grid = 4096 (XCD-swizzled), block 256. LDS ~39 KB -> 4 blocks/CU.
// ---------------------------------------------------------------------------
__global__ __launch_bounds__(256, 4) void attn_kernel(
    const u16* __restrict__ qh, const u16* __restrict__ kh, const u16* __restrict__ vt,
    const u16* __restrict__ erkb, const u16* __restrict__ ervt,
    const float* __restrict__ xmask, u16* __restrict__ yf)
{
    __shared__ u16   Sb[16][1032];      // raw exp(score) bf16
    __shared__ u16   sw[16][168];       // phase A: srel; phase B: wrel (raw scale)
    __shared__ float red[4][16][2];     // per-wave {sum, phi}
    __shared__ float invrow[16];

    const int gid = blockIdx.x;
    const int x8 = gid & 7, idx = gid >> 3;      // 512 per XCD class
    const int bh = x8 + 8 * (idx >> 6);
    const int i0 = (idx & 63) * 16;
    const int b = bh >> 3, h = bh & 7;
    const int tid = threadIdx.x, wave = tid >> 6, lane = tid & 63;
    const int quad = lane >> 4, l16 = lane & 15;

    // Q A-frags (rows i0+l16)
    const u16* qrow = qh + (((size_t)bh * T_ + i0 + l16) << 6);
    const short8 qa0 = *(const short8*)(qrow + quad * 8);
    const short8 qa1 = *(const short8*)(qrow + 32 + quad * 8);

    // ---- phase 1: srel via MFMA ----
    for (int tile = wave; tile < 9; tile += 4) {
        const int rel = tile * 16 + l16;
        const int rl = rel > 128 ? 128 : rel;
        const u16* ep = erkb + rl * 64 + quad * 8;
        const short8 b0 = *(const short8*)(ep);
        const short8 b1 = *(const short8*)(ep + 32);
        f32x4 m = {0.f, 0.f, 0.f, 0.f};
        m = __builtin_amdgcn_mfma_f32_16x16x32_bf16(qa0, b0, m, 0, 0, 0);
        m = __builtin_amdgcn_mfma_f32_16x16x32_bf16(qa1, b1, m, 0, 0, 0);
        if (rel < 129) {
#pragma unroll
            for (int rix = 0; rix < 4; ++rix) sw[quad * 4 + rix][rel] = f2b(m[rix]);
        }
    }
    __syncthreads();

    // ---- phase 2: QK^T + exp (raw) -> Sb; fp32 row sums ----
    float psum[4] = {0.f, 0.f, 0.f, 0.f};
    float phi [4] = {0.f, 0.f, 0.f, 0.f};
    float slo_c[4], shi_c[4];
#pragma unroll
    for (int rix = 0; rix < 4; ++rix) {
        const int row = quad * 4 + rix;
        slo_c[rix] = b2f(sw[row][0]);
        shi_c[rix] = b2f(sw[row][2 * K_]);
    }
    {
        const u16* kb = kh + ((size_t)bh << 16);
#pragma unroll
        for (int ct = 0; ct < 16; ++ct) {
            const int j0 = wave * 256 + ct * 16;
            const u16* krow = kb + ((size_t)(j0 + l16) << 6);
            const short8 kb0 = *(const short8*)(krow + quad * 8);
            const short8 kb1 = *(const short8*)(krow + 32 + quad * 8);
            const int j = j0 + l16;
            const float xmv = xmask[b * T_ + j];
            f32x4 acc = {0.f, 0.f, 0.f, 0.f};
            acc = __builtin_amdgcn_mfma_f32_16x16x32_bf16(qa0, kb0, acc, 0, 0, 0);
            acc = __builtin_amdgcn_mfma_f32_16x16x32_bf16(qa1, kb1, acc, 0, 0, 0);
            const int dd = j0 - i0;                 // wave-uniform tile offset
            if (dd <= -79) {
#pragma unroll
                for (int rix = 0; rix < 4; ++rix) {
                    const int row = quad * 4 + rix;
                    float val = acc[rix] * 0.125f + slo_c[rix];
                    val = (xmv > 0.f) ? val : -1e9f;
                    const u16 pb = f2b(__expf(fminf(val, 30.f)));
                    const float er = b2f(pb);
                    Sb[row][j] = pb;
                    psum[rix] += er;
                }
            } else if (dd >= 79) {
#pragma unroll
                for (int rix = 0; rix < 4; ++rix) {
                    const int row = quad * 4 + rix;
                    float val = acc[rix] * 0.125f + shi_c[rix];
                    val = (xmv > 0.f) ? val : -1e9f;
                    const u16 pb = f2b(__expf(fminf(val, 30.f)));
                    const float er = b2f(pb);
                    Sb[row][j] = pb;
                    psum[rix] += er;
                    phi[rix]  += er;
                }
            } else {
#pragma unroll
                for (int rix = 0; rix < 4; ++rix) {
                    const int row = quad * 4 + rix;
                    const int i = i0 + row;
                    int rel = j - i;
                    rel = (rel < -K_) ? -K_ : (rel > K_) ? K_ : rel;
                    float val = acc[rix] * 0.125f + b2f(sw[row][rel + K_]);
                    val = (xmv > 0.f) ? val : -1e9f;
                    const u16 pb = f2b(__expf(fminf(val, 30.f)));
                    const float er = b2f(pb);
                    Sb[row][j] = pb;
                    psum[rix] += er;
                    phi[rix]  += (j >= i + K_) ? er : 0.f;
                }
            }
        }
#pragma unroll
        for (int m = 1; m < 16; m <<= 1)
#pragma unroll
            for (int rix = 0; rix < 4; ++rix) {
                psum[rix] += __shfl_xor(psum[rix], m);
                phi[rix]  += __shfl_xor(phi[rix], m);
            }
        if (l16 == 0)
#pragma unroll
            for (int rix = 0; rix < 4; ++rix) {
                const int row = quad * 4 + rix;
                red[wave][row][0] = psum[rix];
                red[wave][row][1] = phi[rix];
            }
    }
    __syncthreads();

    // ---- phase 3: wrel (raw) from Sb; slo by complement; invrow ----
    {
        const int rr = tid >> 4;        // 0..15
        const int c0 = tid & 15;
        const float sumrow = red[0][rr][0] + red[1][rr][0] + red[2][rr][0] + red[3][rr][0];
        const float phirow = red[0][rr][1] + red[1][rr][1] + red[2][rr][1] + red[3][rr][1];
        float intsum = 0.f;
        for (int rel = c0; rel < 168; rel += 16) {
            if (rel == 0 || rel == 2 * K_) continue;
            u16 v = 0;
            if (rel < 2 * K_) {
                const int j = i0 + rr + rel - K_;
                if (j >= 0 && j < T_) v = Sb[rr][j];
                intsum += b2f(v);
            }
            sw[rr][rel] = v;
        }
        intsum += __shfl_xor(intsum, 1);
        intsum += __shfl_xor(intsum, 2);
        intsum += __shfl_xor(intsum, 4);
        intsum += __shfl_xor(intsum, 8);
        if (c0 == 0) {
            sw[rr][2 * K_] = f2b(phirow);
            sw[rr][0]      = f2b(sumrow - intsum - phirow);
            invrow[rr]     = 1.0f / sumrow;
        }
    }
    __syncthreads();

    // ---- phase 4: PV + rel-v via MFMA (transposed); scale by 1/rowsum ----
    {
        const int dh = wave * 16 + l16;
        const u16* vb = vt + ((size_t)bh << 16) + ((size_t)dh << 10);
        f32x4 og = {0.f, 0.f, 0.f, 0.f};
#pragma unroll 4
        for (int ks = 0; ks < 32; ++ks) {
            const short8 af = *(const short8*)(vb + (ks << 5) + quad * 8);
            const short8 p0 = *(const short8*)(&Sb[l16][ks * 32 + quad * 8]);
            og = __builtin_amdgcn_mfma_f32_16x16x32_bf16(af, p0, og, 0, 0, 0);
        }
        const u16* ep = ervt + dh * 160;
#pragma unroll
        for (int kt = 0; kt < 5; ++kt) {
            const short8 af = *(const short8*)(ep + kt * 32 + quad * 8);
            const short8 p0 = *(const short8*)(&sw[l16][kt * 32 + quad * 8]);
            og = __builtin_amdgcn_mfma_f32_16x16x32_bf16(af, p0, og, 0, 0, 0);
        }
        const float iv = invrow[l16];
        ushort4 u0;
        u0.x = f2b(og[0] * iv); u0.y = f2b(og[1] * iv);
        u0.z = f2b(og[2] * iv); u0.w = f2b(og[3] * iv);
        *(ushort4*)(yf + (((size_t)b * T_ + i0 + l16) << 9) + (h << 6) + wave * 16 + quad * 4) = u0;
    }
}

// ---------------------------------------------------------------------------
// Kernel 3: output projection, 128x128 tile, BK=64, A+B staged in LDS.
// grid = (4, 8, 8); block 256. out[b,o,t] = (Wo[o,:].yf[b,t,:] + bo[o])*xm
// ---------------------------------------------------------------------------
__global__ __launch_bounds__(256) void outproj_mfma(
    const u16* __restrict__ yf, const u16* __restrict__ Woh, const float* __restrict__ bo,
    const float* __restrict__ xmask, float* __restrict__ out)
{
    __shared__ u16 As[128][72];   // Wo rows (o)
    __shared__ u16 Bs[128][72];   // yf rows (t)

    const int o0 = blockIdx.x * 128;
    const int t0 = blockIdx.y * 128;
    const int b  = blockIdx.z;
    const int tid = threadIdx.x, wave = tid >> 6, lane = tid & 63;
    const int quad = lane >> 4, l16 = lane & 15;
    const int wr = wave >> 1, wc = wave & 1;

    const u16* Abase = Woh + ((size_t)o0 << 9);
    const u16* Bbase = yf + (((size_t)b * T_ + t0) << 9);

    int srow[4], scol[4];
#pragma unroll
    for (int p = 0; p < 4; ++p) {
        const int idx = p * 256 + tid;
        srow[p] = idx >> 3;
        scol[p] = (idx & 7) * 8;
    }

    f32x4 acc[4][4];
#pragma unroll
    for (int mi = 0; mi < 4; ++mi)
#pragma unroll
        for (int ni = 0; ni < 4; ++ni) acc[mi][ni] = (f32x4){0.f, 0.f, 0.f, 0.f};

    uint4 ra[4], rb[4];
#pragma unroll
    for (int p = 0; p < 4; ++p) {
        ra[p] = *(const uint4*)(Abase + ((size_t)srow[p] << 9) + scol[p]);
        rb[p] = *(const uint4*)(Bbase + ((size_t)srow[p] << 9) + scol[p]);
    }
#pragma unroll 1
    for (int kt = 0; kt < 8; ++kt) {
        __syncthreads();
#pragma unroll
        for (int p = 0; p < 4; ++p) {
            *(uint4*)&As[srow[p]][scol[p]] = ra[p];
            *(uint4*)&Bs[srow[p]][scol[p]] = rb[p];
        }
        __syncthreads();
        if (kt < 7) {
            const int cn = (kt + 1) * 64;
#pragma unroll
            for (int p = 0; p < 4; ++p) {
                ra[p] = *(const uint4*)(Abase + ((size_t)srow[p] << 9) + cn + scol[p]);
                rb[p] = *(const uint4*)(Bbase + ((size_t)srow[p] << 9) + cn + scol[p]);
            }
        }
#pragma unroll
        for (int kk = 0; kk < 64; kk += 32) {
            short8 af[4], bf[4];
#pragma unroll
            for (int mi = 0; mi < 4; ++mi)
                af[mi] = *(const short8*)(&As[wr * 64 + mi * 16 + l16][kk + quad * 8]);
#pragma unroll
            for (int ni = 0; ni < 4; ++ni)
                bf[ni] = *(const short8*)(&Bs[wc * 64 + ni * 16 + l16][kk + quad * 8]);
#pragma unroll
            for (int mi = 0; mi < 4; ++mi)
#pragma unroll
                for (int ni = 0; ni < 4; ++ni)
                    acc[mi][ni] = __builtin_amdgcn_mfma_f32_16x16x32_bf16(af[mi], bf[ni], acc[mi][ni], 0, 0, 0);
        }
    }

#pragma unroll
    for (int ni = 0; ni < 4; ++ni) {
        const int t = t0 + wc * 64 + ni * 16 + l16;
        const float xmv = xmask[b * T_ + t];
#pragma unroll
        for (int mi = 0; mi < 4; ++mi) {
#pragma unroll
            for (int rix = 0; rix < 4; ++rix) {
                const int o = o0 + wr * 64 + mi * 16 + quad * 4 + rix;
                out[(((size_t)(b * C_ + o)) << 10) + t] = (acc[mi][ni][rix] + bo[o]) * xmv;
            }
        }
    }
}

// ---------------------------------------------------------------------------
extern "C" void kernel_launch(void* const* d_in, const int* in_sizes, int n_in,
                              void* d_out, int out_size, void* d_ws, size_t ws_size,
                              hipStream_t stream) {
    const float* x     = (const float*)d_in[0];
    const float* xmask = (const float*)d_in[1];
    const float* Wq    = (const float*)d_in[2];
    const float* bq    = (const float*)d_in[3];
    const float* Wk    = (const float*)d_in[4];
    const float* bk    = (const float*)d_in[5];
    const float* Wv    = (const float*)d_in[6];
    const float* bv    = (const float*)d_in[7];
    const float* Wo    = (const float*)d_in[8];
    const float* bo    = (const float*)d_in[9];
    const float* erk   = (const float*)d_in[10];
    const float* erv   = (const float*)d_in[11];

    // workspace (bf16):
    //   xt [B,T,C]    @ 0         (8 MB)
    //   Wh [4,C,C]    @ 8 MB      (2 MB)
    //   qh [B,H,T,D]  @ 10 MB     (8 MB)
    //   kh            @ 18 MB     (8 MB)
    //   vt [B,H,D,T]  @ 26 MB     (8 MB)
    //   yf [B,T,C]    @ 34 MB     (8 MB)
    //   ervt [64,160] @ 44040192  (20480 B)
    //   erkb [129,64] @ 44060672  (16512 B)
    const size_t need = 44077184;
    if (ws_size < need) return;
    u16* xt   = (u16*)d_ws;
    u16* Wh   = (u16*)((char*)d_ws + 8388608);
    u16* qh   = (u16*)((char*)d_ws + 10485760);
    u16* kh   = (u16*)((char*)d_ws + 18874368);
    u16* vt   = (u16*)((char*)d_ws + 27262976);
    u16* yf   = (u16*)((char*)d_ws + 35651584);
    u16* ervt = (u16*)((char*)d_ws + 44040192);
    u16* erkb = (u16*)((char*)d_ws + 44060672);
    float* out = (float*)d_out;

    cast_x_kernel<<<dim3(T_ / 64, C_ / 64, B_), 256, 0, stream>>>(x, xt);
    cast_w_kernel<<<dim3(1024), 256, 0, stream>>>(Wq, Wk, Wv, Wo, Wh);
    cast_rel_kernel<<<dim3(73), 256, 0, stream>>>(erk, erv, ervt, erkb);
    proj_mfma<<<dim3(T_ / 128, 4, 3 * B_), 256, 0, stream>>>(
        xt, Wh, bq, bk, bv, qh, kh, vt);
    attn_kernel<<<dim3(4096), 256, 0, stream>>>(
        qh, kh, vt, erkb, ervt, xmask, yf);
    outproj_mfma<<<dim3(4, 8, B_), 256, 0, stream>>>(
        yf, Wh + ((size_t)3 << 18), bo, xmask, out);
}

// Round 10
// 237.467 us; speedup vs baseline: 1.4685x; 1.4685x over previous
//
#include <hip/hip_runtime.h>

// (B,C,T)=(8,512,1024), H=8, D=64, K=64, REL=129. I/O fp32; internal bf16.
#define B_   8
#define C_   512
#define T_   1024
#define H_   8
#define D_   64
#define K_   64
#define REL_ 129

typedef unsigned short u16;
typedef __attribute__((ext_vector_type(8))) short short8;   // 8 bf16 (4 VGPRs)
typedef __attribute__((ext_vector_type(4))) float f32x4;

__device__ __forceinline__ float b2f(u16 u) {
    return __uint_as_float(((unsigned)u) << 16);
}
__device__ __forceinline__ u16 f2b(float f) {
    unsigned x = __float_as_uint(f);
    x += 0x7fffu + ((x >> 16) & 1u);   // RNE
    return (u16)(x >> 16);
}

// ---------------------------------------------------------------------------
// Kernel 0: all input casts in one launch.
//   blk [0,1024)    : x -> xt[b][t][c] bf16 (transpose)
//   blk [1024,2048) : Wq/Wk/Wv/Wo -> Wh[4][512][512] bf16
//   blk [2048,2121) : ervt[d][rel] [64][160] pad0 ; erkb[rel][d] [129][64]
// ---------------------------------------------------------------------------
__global__ __launch_bounds__(256) void cast_all_kernel(
    const float* __restrict__ x,
    const float* __restrict__ Wq, const float* __restrict__ Wk,
    const float* __restrict__ Wv, const float* __restrict__ Wo,
    const float* __restrict__ erk, const float* __restrict__ erv,
    u16* __restrict__ xt, u16* __restrict__ Wh,
    u16* __restrict__ ervt, u16* __restrict__ erkb)
{
    __shared__ u16 tile[64][72];
    const int blk = blockIdx.x;
    const int tid = threadIdx.x;
    if (blk < 1024) {
        const int t0 = (blk & 15) * 64, c0 = ((blk >> 4) & 7) * 64, b = blk >> 7;
        const int f = tid & 15, r0 = tid >> 4;
#pragma unroll
        for (int p = 0; p < 4; ++p) {
            const int c = r0 + p * 16;
            const float4 v = *(const float4*)(x + ((size_t)b * C_ + c0 + c) * T_ + t0 + f * 4);
            tile[c][f * 4 + 0] = f2b(v.x);
            tile[c][f * 4 + 1] = f2b(v.y);
            tile[c][f * 4 + 2] = f2b(v.z);
            tile[c][f * 4 + 3] = f2b(v.w);
        }
        __syncthreads();
#pragma unroll
        for (int p = 0; p < 4; ++p) {
            const int t = r0 + p * 16;
            ushort4 u;
            u.x = tile[f * 4 + 0][t];
            u.y = tile[f * 4 + 1][t];
            u.z = tile[f * 4 + 2][t];
            u.w = tile[f * 4 + 3][t];
            *(ushort4*)(xt + ((size_t)b * T_ + t0 + t) * C_ + c0 + f * 4) = u;
        }
    } else if (blk < 2048) {
        const int gid = (blk - 1024) * 256 + tid;
        const int s = gid >> 16;
        const int off = (gid & 65535) * 4;
        const float* W = (s == 0) ? Wq : (s == 1) ? Wk : (s == 2) ? Wv : Wo;
        const float4 v = *(const float4*)(W + off);
        ushort4 u;
        u.x = f2b(v.x); u.y = f2b(v.y); u.z = f2b(v.z); u.w = f2b(v.w);
        *(ushort4*)(Wh + ((size_t)s << 18) + off) = u;
    } else {
        const int idx = (blk - 2048) * 256 + tid;
        if (idx < 64 * 160) {
            const int d = idx / 160, rel = idx % 160;
            ervt[idx] = (rel < REL_) ? f2b(erv[rel * D_ + d]) : (u16)0;
        } else {
            const int j = idx - 64 * 160;
            if (j < REL_ * D_) erkb[j] = f2b(erk[j]);
        }
    }
}

// ---------------------------------------------------------------------------
// Kernel 1: QKV projection via MFMA (R8 64-tile: 12 blocks/CU TLP).
// W strip staged in LDS (BK=64, pipelined). grid = (T/64, H, 3*B), block 256.
// ---------------------------------------------------------------------------
__global__ __launch_bounds__(256) void proj_mfma(
    const u16* __restrict__ xt, const u16* __restrict__ Wh,
    const float* __restrict__ bq, const float* __restrict__ bk, const float* __restrict__ bv,
    u16* __restrict__ qh, u16* __restrict__ kh, u16* __restrict__ vt)
{
    __shared__ u16 Wt[64][72];

    const int t0 = blockIdx.x * 64;
    const int h  = blockIdx.y;
    const int sel = blockIdx.z >> 3;
    const int b   = blockIdx.z & 7;
    const int tid = threadIdx.x, wave = tid >> 6, lane = tid & 63;
    const int quad = lane >> 4, l16 = lane & 15;

    const u16* Wbase = Wh + ((size_t)sel << 18) + ((size_t)(h * 64) << 9);
    const u16* A = xt + (((size_t)b * T_ + t0 + wave * 16 + l16) << 9);

    const int so = tid >> 2;
    const int sc = (tid & 3) * 16;
    const u16* wsrc = Wbase + ((size_t)so << 9) + sc;

    f32x4 acc[4] = {{0.f,0.f,0.f,0.f},{0.f,0.f,0.f,0.f},{0.f,0.f,0.f,0.f},{0.f,0.f,0.f,0.f}};

    uint4 wv0 = *(const uint4*)(wsrc);
    uint4 wv1 = *(const uint4*)(wsrc + 8);
#pragma unroll 1
    for (int i = 0; i < 8; ++i) {
        const int c0 = i * 64;
        __syncthreads();
        *(uint4*)&Wt[so][sc] = wv0;
        *(uint4*)&Wt[so][sc + 8] = wv1;
        __syncthreads();
        if (i < 7) {
            wv0 = *(const uint4*)(wsrc + c0 + 64);
            wv1 = *(const uint4*)(wsrc + c0 + 72);
        }
#pragma unroll
        for (int kk = 0; kk < 64; kk += 32) {
            const short8 af = *(const short8*)(A + c0 + kk + quad * 8);
#pragma unroll
            for (int nt = 0; nt < 4; ++nt) {
                const short8 bf = *(const short8*)(&Wt[nt * 16 + l16][kk + quad * 8]);
                acc[nt] = __builtin_amdgcn_mfma_f32_16x16x32_bf16(af, bf, acc[nt], 0, 0, 0);
            }
        }
    }

    const float* bias = (sel == 0) ? bq : (sel == 1) ? bk : bv;
    const int bh = b * 8 + h;
#pragma unroll
    for (int nt = 0; nt < 4; ++nt) {
        const int d = nt * 16 + l16;
        const float bo = bias[h * 64 + d];
#pragma unroll
        for (int rix = 0; rix < 4; ++rix) {
            const int t = t0 + wave * 16 + quad * 4 + rix;
            const u16 val = f2b(acc[nt][rix] + bo);
            if (sel == 2) {
                vt[(((size_t)bh * 64 + d) << 10) + t] = val;
            } else {
                u16* dst = sel ? kh : qh;
                dst[(((size_t)bh * T_ + t) << 6) + d] = val;
            }
        }
    }
}

// ---------------------------------------------------------------------------
// Kernel 2: MFMA attention, 32 q-rows/block, deferred normalization,
// MERGED barrier-free QK+PV: wave w computes its j-quarter scores (all 32
// rows) then immediately accumulates partial O over that quarter for all 4
// d-strips (same-wave LDS producer/consumer, no __syncthreads). Cross-wave
// O reduction staged in LDS aliased over dead Sb rows.
// grid = 2048 (XCD-swizzled), block 256. LDS ~78 KB -> 2 blocks/CU.
// ---------------------------------------------------------------------------
__global__ __launch_bounds__(256, 2) void attn_kernel(
    const u16* __restrict__ qh, const u16* __restrict__ kh, const u16* __restrict__ vt,
    const u16* __restrict__ erkb, const u16* __restrict__ ervt,
    const float* __restrict__ xmask, u16* __restrict__ yf)
{
    __shared__ u16   Sb[32][1032];      // raw exp(score) bf16; later og staging
    __shared__ u16   sw[32][168];      // phase A: srel; phase B: wrel (raw)
    __shared__ float red[4][32][2];    // per-wave {sum, phi}
    __shared__ float invrow[32];

    const int gid = blockIdx.x;
    const int x8 = gid & 7, r5 = gid >> 3;
    const int bh = x8 + 8 * (r5 >> 5);
    const int i0 = (r5 & 31) * 32;
    const int b = bh >> 3, h = bh & 7;
    const int tid = threadIdx.x, wave = tid >> 6, lane = tid & 63;
    const int quad = lane >> 4, l16 = lane & 15;

    // Q A-frags for both 16-row groups
    short8 qa[2][2];
#pragma unroll
    for (int g = 0; g < 2; ++g) {
        const u16* qrow = qh + (((size_t)bh * T_ + i0 + g * 16 + l16) << 6);
        qa[g][0] = *(const short8*)(qrow + quad * 8);
        qa[g][1] = *(const short8*)(qrow + 32 + quad * 8);
    }

    // ---- phase 1: srel via MFMA ----
    for (int tile = wave; tile < 9; tile += 4) {
        const int rel = tile * 16 + l16;
        const int rl = rel > 128 ? 128 : rel;
        const u16* ep = erkb + rl * 64 + quad * 8;
        const short8 b0 = *(const short8*)(ep);
        const short8 b1 = *(const short8*)(ep + 32);
#pragma unroll
        for (int g = 0; g < 2; ++g) {
            f32x4 m = {0.f, 0.f, 0.f, 0.f};
            m = __builtin_amdgcn_mfma_f32_16x16x32_bf16(qa[g][0], b0, m, 0, 0, 0);
            m = __builtin_amdgcn_mfma_f32_16x16x32_bf16(qa[g][1], b1, m, 0, 0, 0);
            if (rel < 129) {
#pragma unroll
                for (int rix = 0; rix < 4; ++rix)
                    sw[g * 16 + quad * 4 + rix][rel] = f2b(m[rix]);
            }
        }
    }
    __syncthreads();                                    // barrier 1

    // srel constants for fully-clamped tiles
    float slo_c[2][4], shi_c[2][4];
#pragma unroll
    for (int g = 0; g < 2; ++g)
#pragma unroll
        for (int rix = 0; rix < 4; ++rix) {
            const int row = g * 16 + quad * 4 + rix;
            slo_c[g][rix] = b2f(sw[row][0]);
            shi_c[g][rix] = b2f(sw[row][2 * K_]);
        }

    // ---- merged QK + exp + partial-PV over this wave's j-quarter ----
    float psum[2][4] = {{0.f,0.f,0.f,0.f},{0.f,0.f,0.f,0.f}};
    float phi [2][4] = {{0.f,0.f,0.f,0.f},{0.f,0.f,0.f,0.f}};
    f32x4 og[4][2];
#pragma unroll
    for (int s = 0; s < 4; ++s)
#pragma unroll
        for (int g = 0; g < 2; ++g) og[s][g] = (f32x4){0.f, 0.f, 0.f, 0.f};

    {
        const u16* kb = kh + ((size_t)bh << 16);
        const u16* vbase = vt + ((size_t)bh << 16);
#pragma unroll 1
        for (int c = 0; c < 8; ++c) {
#pragma unroll
            for (int half = 0; half < 2; ++half) {
                const int ct = c * 2 + half;
                const int j0 = wave * 256 + ct * 16;
                const u16* krow = kb + ((size_t)(j0 + l16) << 6);
                const short8 kb0 = *(const short8*)(krow + quad * 8);
                const short8 kb1 = *(const short8*)(krow + 32 + quad * 8);
                const int j = j0 + l16;
                const float xmv = xmask[b * T_ + j];
#pragma unroll
                for (int g = 0; g < 2; ++g) {
                    f32x4 acc = {0.f, 0.f, 0.f, 0.f};
                    acc = __builtin_amdgcn_mfma_f32_16x16x32_bf16(qa[g][0], kb0, acc, 0, 0, 0);
                    acc = __builtin_amdgcn_mfma_f32_16x16x32_bf16(qa[g][1], kb1, acc, 0, 0, 0);
                    const int dd = j0 - (i0 + g * 16);
                    if (dd <= -79) {
#pragma unroll
                        for (int rix = 0; rix < 4; ++rix) {
                            const int row = g * 16 + quad * 4 + rix;
                            float val = acc[rix] * 0.125f + slo_c[g][rix];
                            val = (xmv > 0.f) ? val : -1e9f;
                            const u16 pb = f2b(__expf(fminf(val, 30.f)));
                            const float er = b2f(pb);
                            Sb[row][j] = pb;
                            psum[g][rix] += er;
                        }
                    } else if (dd >= 79) {
#pragma unroll
                        for (int rix = 0; rix < 4; ++rix) {
                            const int row = g * 16 + quad * 4 + rix;
                            float val = acc[rix] * 0.125f + shi_c[g][rix];
                            val = (xmv > 0.f) ? val : -1e9f;
                            const u16 pb = f2b(__expf(fminf(val, 30.f)));
                            const float er = b2f(pb);
                            Sb[row][j] = pb;
                            psum[g][rix] += er;
                            phi[g][rix]  += er;
                        }
                    } else {
#pragma unroll
                        for (int rix = 0; rix < 4; ++rix) {
                            const int row = g * 16 + quad * 4 + rix;
                            const int i = i0 + row;
                            int rel = j - i;
                            rel = (rel < -K_) ? -K_ : (rel > K_) ? K_ : rel;
                            float val = acc[rix] * 0.125f + b2f(sw[row][rel + K_]);
                            val = (xmv > 0.f) ? val : -1e9f;
                            const u16 pb = f2b(__expf(fminf(val, 30.f)));
                            const float er = b2f(pb);
                            Sb[row][j] = pb;
                            psum[g][rix] += er;
                            phi[g][rix]  += (j >= i + K_) ? er : 0.f;
                        }
                    }
                }
            }
            // partial PV for this 32-column chunk (same-wave data, no barrier)
            const int kc = wave * 256 + c * 32;
            const short8 pb0 = *(const short8*)(&Sb[l16][kc + quad * 8]);
            const short8 pb1 = *(const short8*)(&Sb[16 + l16][kc + quad * 8]);
#pragma unroll
            for (int s = 0; s < 4; ++s) {
                const short8 af = *(const short8*)(vbase + ((size_t)(s * 16 + l16) << 10) + kc + quad * 8);
                og[s][0] = __builtin_amdgcn_mfma_f32_16x16x32_bf16(af, pb0, og[s][0], 0, 0, 0);
                og[s][1] = __builtin_amdgcn_mfma_f32_16x16x32_bf16(af, pb1, og[s][1], 0, 0, 0);
            }
        }
#pragma unroll
        for (int m = 1; m < 16; m <<= 1)
#pragma unroll
            for (int g = 0; g < 2; ++g)
#pragma unroll
                for (int rix = 0; rix < 4; ++rix) {
                    psum[g][rix] += __shfl_xor(psum[g][rix], m);
                    phi[g][rix]  += __shfl_xor(phi[g][rix], m);
                }
        if (l16 == 0)
#pragma unroll
            for (int g = 0; g < 2; ++g)
#pragma unroll
                for (int rix = 0; rix < 4; ++rix) {
                    const int row = g * 16 + quad * 4 + rix;
                    red[wave][row][0] = psum[g][rix];
                    red[wave][row][1] = phi[g][rix];
                }
    }
    __syncthreads();                                    // barrier 2

    // ---- wrel (raw) from Sb; slo by complement; invrow ----
    {
        const int rr = tid >> 3;        // 0..31
        const int c0 = tid & 7;
        const float sumrow = red[0][rr][0] + red[1][rr][0] + red[2][rr][0] + red[3][rr][0];
        const float phirow = red[0][rr][1] + red[1][rr][1] + red[2][rr][1] + red[3][rr][1];
        float intsum = 0.f;
        for (int rel = c0; rel < 168; rel += 8) {
            if (rel == 0 || rel == 2 * K_) continue;
            u16 v = 0;
            if (rel < 2 * K_) {
                const int j = i0 + rr + rel - K_;
                if (j >= 0 && j < T_) v = Sb[rr][j];
                intsum += b2f(v);
            }
            sw[rr][rel] = v;
        }
        intsum += __shfl_xor(intsum, 1);
        intsum += __shfl_xor(intsum, 2);
        intsum += __shfl_xor(intsum, 4);
        if (c0 == 0) {
            sw[rr][2 * K_] = f2b(phirow);
            sw[rr][0]      = f2b(sumrow - intsum - phirow);
            invrow[rr]     = 1.0f / sumrow;
        }
    }
    __syncthreads();                                    // barrier 3

    // ---- stage og partials into LDS (aliased over dead Sb rows) ----
    float* fog = (float*)&Sb[0][0];                     // 4 waves x 2048 floats = 32 KB
#pragma unroll
    for (int s = 0; s < 4; ++s)
#pragma unroll
        for (int g = 0; g < 2; ++g)
            *(f32x4*)&fog[wave * 2048 + ((s * 2 + g) * 64 + lane) * 4] = og[s][g];
    __syncthreads();                                    // barrier 4

    // ---- owner wave (strip = wave): reduce 4 partials + rel-v MFMA; store ----
    {
        const int dh = wave * 16 + l16;
        const u16* ep = ervt + dh * 160;
        f32x4 accg[2];
#pragma unroll
        for (int g = 0; g < 2; ++g) {
            const int base = ((wave * 2 + g) * 64 + lane) * 4;
            f32x4 a0 = *(const f32x4*)&fog[base];
            f32x4 a1 = *(const f32x4*)&fog[2048 + base];
            f32x4 a2 = *(const f32x4*)&fog[4096 + base];
            f32x4 a3 = *(const f32x4*)&fog[6144 + base];
#pragma unroll
            for (int rix = 0; rix < 4; ++rix)
                accg[g][rix] = (a0[rix] + a1[rix]) + (a2[rix] + a3[rix]);
        }
#pragma unroll
        for (int kt = 0; kt < 5; ++kt) {
            const short8 af = *(const short8*)(ep + kt * 32 + quad * 8);
            const short8 p0 = *(const short8*)(&sw[l16][kt * 32 + quad * 8]);
            const short8 p1 = *(const short8*)(&sw[16 + l16][kt * 32 + quad * 8]);
            accg[0] = __builtin_amdgcn_mfma_f32_16x16x32_bf16(af, p0, accg[0], 0, 0, 0);
            accg[1] = __builtin_amdgcn_mfma_f32_16x16x32_bf16(af, p1, accg[1], 0, 0, 0);
        }
        const int dbase = (h << 6) + wave * 16 + quad * 4;
#pragma unroll
        for (int g = 0; g < 2; ++g) {
            const float iv = invrow[g * 16 + l16];
            ushort4 u;
            u.x = f2b(accg[g][0] * iv); u.y = f2b(accg[g][1] * iv);
            u.z = f2b(accg[g][2] * iv); u.w = f2b(accg[g][3] * iv);
            *(ushort4*)(yf + (((size_t)b * T_ + i0 + g * 16 + l16) << 9) + dbase) = u;
        }
    }
}

// ---------------------------------------------------------------------------
// Kernel 3: output projection via MFMA (R8 64-tile). yf tile staged in LDS.
// grid = (C/64, B*T/64), block 256.
// ---------------------------------------------------------------------------
__global__ __launch_bounds__(256) void outproj_mfma(
    const u16* __restrict__ yf, const u16* __restrict__ Woh, const float* __restrict__ bo,
    const float* __restrict__ xmask, float* __restrict__ out)
{
    __shared__ u16 Yt[64][72];

    const int o0 = blockIdx.x * 64;
    const int b  = blockIdx.y >> 4;
    const int t0 = (blockIdx.y & 15) * 64;
    const int tid = threadIdx.x, wave = tid >> 6, lane = tid & 63;
    const int quad = lane >> 4, l16 = lane & 15;

    const u16* A = Woh + ((size_t)(o0 + wave * 16 + l16) << 9);

    const int so = tid >> 2;
    const int sc = (tid & 3) * 16;
    const u16* ysrc = yf + (((size_t)b * T_ + t0 + so) << 9) + sc;

    f32x4 acc[4] = {{0.f,0.f,0.f,0.f},{0.f,0.f,0.f,0.f},{0.f,0.f,0.f,0.f},{0.f,0.f,0.f,0.f}};

    uint4 wv0 = *(const uint4*)(ysrc);
    uint4 wv1 = *(const uint4*)(ysrc + 8);
#pragma unroll 1
    for (int i = 0; i < 8; ++i) {
        const int c0 = i * 64;
        __syncthreads();
        *(uint4*)&Yt[so][sc] = wv0;
        *(uint4*)&Yt[so][sc + 8] = wv1;
        __syncthreads();
        if (i < 7) {
            wv0 = *(const uint4*)(ysrc + c0 + 64);
            wv1 = *(const uint4*)(ysrc + c0 + 72);
        }
#pragma unroll
        for (int kk = 0; kk < 64; kk += 32) {
            const short8 af = *(const short8*)(A + c0 + kk + quad * 8);
#pragma unroll
            for (int nt = 0; nt < 4; ++nt) {
                const short8 bf = *(const short8*)(&Yt[nt * 16 + l16][kk + quad * 8]);
                acc[nt] = __builtin_amdgcn_mfma_f32_16x16x32_bf16(af, bf, acc[nt], 0, 0, 0);
            }
        }
    }

#pragma unroll
    for (int nt = 0; nt < 4; ++nt) {
        const int t = t0 + nt * 16 + l16;
        const float xmv = xmask[b * T_ + t];
#pragma unroll
        for (int rix = 0; rix < 4; ++rix) {
            const int o = o0 + wave * 16 + quad * 4 + rix;
            out[((size_t)b * C_ + o) * T_ + t] = (acc[nt][rix] + bo[o]) * xmv;
        }
    }
}

// ---------------------------------------------------------------------------
extern "C" void kernel_launch(void* const* d_in, const int* in_sizes, int n_in,
                              void* d_out, int out_size, void* d_ws, size_t ws_size,
                              hipStream_t stream) {
    const float* x     = (const float*)d_in[0];
    const float* xmask = (const float*)d_in[1];
    const float* Wq    = (const float*)d_in[2];
    const float* bq    = (const float*)d_in[3];
    const float* Wk    = (const float*)d_in[4];
    const float* bk    = (const float*)d_in[5];
    const float* Wv    = (const float*)d_in[6];
    const float* bv    = (const float*)d_in[7];
    const float* Wo    = (const float*)d_in[8];
    const float* bo    = (const float*)d_in[9];
    const float* erk   = (const float*)d_in[10];
    const float* erv   = (const float*)d_in[11];

    // workspace (bf16):
    //   xt [B,T,C]    @ 0         (8 MB)
    //   Wh [4,C,C]    @ 8 MB      (2 MB)
    //   qh [B,H,T,D]  @ 10 MB     (8 MB)
    //   kh            @ 18 MB     (8 MB)
    //   vt [B,H,D,T]  @ 26 MB     (8 MB)
    //   yf [B,T,C]    @ 34 MB     (8 MB)
    //   ervt [64,160] @ 44040192  (20480 B)
    //   erkb [129,64] @ 44060672  (16512 B)
    const size_t need = 44077184;
    if (ws_size < need) return;
    u16* xt   = (u16*)d_ws;
    u16* Wh   = (u16*)((char*)d_ws + 8388608);
    u16* qh   = (u16*)((char*)d_ws + 10485760);
    u16* kh   = (u16*)((char*)d_ws + 18874368);
    u16* vt   = (u16*)((char*)d_ws + 27262976);
    u16* yf   = (u16*)((char*)d_ws + 35651584);
    u16* ervt = (u16*)((char*)d_ws + 44040192);
    u16* erkb = (u16*)((char*)d_ws + 44060672);
    float* out = (float*)d_out;

    cast_all_kernel<<<dim3(2121), 256, 0, stream>>>(
        x, Wq, Wk, Wv, Wo, erk, erv, xt, Wh, ervt, erkb);
    proj_mfma<<<dim3(T_ / 64, H_, 3 * B_), 256, 0, stream>>>(
        xt, Wh, bq, bk, bv, qh, kh, vt);
    attn_kernel<<<dim3(2048), 256, 0, stream>>>(
        qh, kh, vt, erkb, ervt, xmask, yf);
    outproj_mfma<<<dim3(C_ / 64, B_ * (T_ / 64)), 256, 0, stream>>>(
        yf, Wh + ((size_t)3 << 18), bo, xmask, out);
}